// Round 4
// baseline (102.640 us; speedup 1.0000x reference)
//
#include <hip/hip_runtime.h>
#include <hip/hip_bf16.h>

#define D_IN 1386
#define EPS 1e-5f
#define CHUNKS 44            // ceil(1386/32)

typedef __attribute__((ext_vector_type(8))) short short8v;
typedef __attribute__((ext_vector_type(4))) float f32x4;
typedef unsigned short ushortt;

__device__ inline unsigned short bf16rne(float f) {
    unsigned int u = __float_as_uint(f);
    u += 0x7FFFu + ((u >> 16) & 1u);
    return (unsigned short)(u >> 16);
}
__device__ inline float bfbits_to_f(unsigned short b) {
    return __uint_as_float(((unsigned int)b) << 16);
}

union S8U { short8v s; unsigned int u[4]; };

// packed pair f32->bf16 (RNE, v_cvt_pk_bf16_f32) + residuals
__device__ inline unsigned int cvt2(float v0, float v1, float& r0, float& r1) {
    union { __hip_bfloat162 b2; unsigned int u; } cv;
    cv.b2 = __float22bfloat162_rn(make_float2(v0, v1));
    r0 = v0 - __uint_as_float((cv.u & 0xFFFFu) << 16);
    r1 = v1 - __uint_as_float(cv.u & 0xFFFF0000u);
    return cv.u;
}
__device__ inline unsigned int cvt2n(float v0, float v1) {
    union { __hip_bfloat162 b2; unsigned int u; } cv;
    cv.b2 = __float22bfloat162_rn(make_float2(v0, v1));
    return cv.u;
}

// ---------------- Kernel 0: precompute triple-split W1 in frag-image order --
// short index: c*6144 + g*512 + l*8 + j -> split_s( w[16T+(l&15)][32c+8*(l>>4)+j] )
// with g = 3*T + s
__global__ __launch_bounds__(256) void prep_w3(const float* __restrict__ w,
                                               ushortt* __restrict__ w3) {
    int idx = blockIdx.x * 256 + threadIdx.x;
    if (idx >= CHUNKS * 6144) return;
    int c   = idx / 6144;
    int rem = idx - c * 6144;
    int g   = rem >> 9;
    int l   = (rem >> 3) & 63;
    int j   = rem & 7;
    int T   = g / 3, s = g - 3 * T;
    int h   = 16 * T + (l & 15);
    int k   = 32 * c + 8 * (l >> 4) + j;
    float v = (k < D_IN) ? w[h * D_IN + k] : 0.f;
    unsigned short hh = bf16rne(v);
    float r1 = v - bfbits_to_f(hh);
    unsigned short mm = bf16rne(r1);
    float r2 = r1 - bfbits_to_f(mm);
    unsigned short ll = bf16rne(r2);
    w3[idx] = (s == 0) ? hh : (s == 1) ? mm : ll;
}

// ---------------- Kernel 1: y = x @ fc1_w.T --------------------------------
// Block: 4 waves, 64 samples (wave wid -> 16 samples). ALL waves walk the
// SAME chunk sequence c=0..43 so the 12KB/chunk B-image is L1-broadcast
// (one L2 fill per CU per chunk). No LDS, no barriers, no K-reduction.
// x prefetched 2 chunks deep to cover ~900cy HBM latency.
__device__ inline void loadA(const float* __restrict__ xrow, int c, int g4,
                             float a[8]) {
    if (c < CHUNKS - 1) {
        const float2* p = (const float2*)(xrow + 32 * c);
#pragma unroll
        for (int i = 0; i < 4; ++i) {
            float2 v = p[i];
            a[2 * i] = v.x; a[2 * i + 1] = v.y;
        }
    } else {
#pragma unroll
        for (int j = 0; j < 8; ++j) {
            int kk = 8 * g4 + j;   // + 1376 = global k
            a[j] = (kk < D_IN - 32 * (CHUNKS - 1)) ? xrow[32 * (CHUNKS - 1) + j] : 0.f;
        }
    }
}

__global__ __launch_bounds__(256) void fc1_mfma(const float* __restrict__ x,
                                                const ushortt* __restrict__ w3,
                                                float* __restrict__ y) {
    const int t    = threadIdx.x;
    const int lane = t & 63;
    const int wid  = t >> 6;
    const int n0   = blockIdx.x * 64 + wid * 16;
    const int r    = lane & 15;
    const int g4   = lane >> 4;
    const float* xrow = x + (size_t)(n0 + r) * D_IN + 8 * g4;

    f32x4 acc[4];
#pragma unroll
    for (int T = 0; T < 4; ++T) acc[T] = (f32x4){0.f, 0.f, 0.f, 0.f};

    float a0[8], a1p[8], a2p[8];
    loadA(xrow, 0, g4, a0);
    loadA(xrow, 1, g4, a1p);

#pragma unroll 2
    for (int c = 0; c < CHUNKS; ++c) {
        // prefetch x two chunks ahead (HBM latency cover)
        if (c + 2 < CHUNKS) loadA(xrow, c + 2, g4, a2p);
        // B fragments for this chunk: identical addresses across the block's
        // 4 waves -> L1 broadcast. 12 x 1KB coalesced dwordx4.
        const short8v* bp = (const short8v*)(w3 + (size_t)c * 6144) + lane;
        short8v B0  = bp[0 * 64],  B1  = bp[1 * 64],  B2  = bp[2 * 64];
        short8v B3  = bp[3 * 64],  B4  = bp[4 * 64],  B5  = bp[5 * 64];
        short8v B6  = bp[6 * 64],  B7  = bp[7 * 64],  B8  = bp[8 * 64];
        short8v B9  = bp[9 * 64],  B10 = bp[10 * 64], B11 = bp[11 * 64];
        // triple-split A in-register (v_cvt_pk_bf16_f32 based)
        S8U Ah, Am, Al;
#pragma unroll
        for (int d = 0; d < 4; ++d) {
            float m0, m1, l0, l1;
            Ah.u[d] = cvt2(a0[2 * d], a0[2 * d + 1], m0, m1);
            Am.u[d] = cvt2(m0, m1, l0, l1);
            Al.u[d] = cvt2n(l0, l1);
        }
        const short8v XH = Ah.s, XM = Am.s, XL = Al.s;
#pragma unroll
        for (int T = 0; T < 4; ++T) {
            const short8v Bh = (T == 0) ? B0 : (T == 1) ? B3 : (T == 2) ? B6 : B9;
            const short8v Bm = (T == 0) ? B1 : (T == 1) ? B4 : (T == 2) ? B7 : B10;
            const short8v Bl = (T == 0) ? B2 : (T == 1) ? B5 : (T == 2) ? B8 : B11;
            f32x4 cacc = acc[T];
            cacc = __builtin_amdgcn_mfma_f32_16x16x32_bf16(XL, Bh, cacc, 0, 0, 0);
            cacc = __builtin_amdgcn_mfma_f32_16x16x32_bf16(XM, Bm, cacc, 0, 0, 0);
            cacc = __builtin_amdgcn_mfma_f32_16x16x32_bf16(XH, Bl, cacc, 0, 0, 0);
            cacc = __builtin_amdgcn_mfma_f32_16x16x32_bf16(XM, Bh, cacc, 0, 0, 0);
            cacc = __builtin_amdgcn_mfma_f32_16x16x32_bf16(XH, Bm, cacc, 0, 0, 0);
            cacc = __builtin_amdgcn_mfma_f32_16x16x32_bf16(XH, Bh, cacc, 0, 0, 0);
            acc[T] = cacc;
        }
        // rotate prefetch registers
#pragma unroll
        for (int j = 0; j < 8; ++j) { a0[j] = a1p[j]; a1p[j] = a2p[j]; }
    }

#pragma unroll
    for (int T = 0; T < 4; ++T)
#pragma unroll
        for (int q = 0; q < 4; ++q)
            y[(size_t)(n0 + 4 * g4 + q) * 64 + 16 * T + r] = acc[T][q];
}

// ---------------- Kernel 2: 64-step LIF recurrence via MFMA (unchanged) -----
__global__ __launch_bounds__(256) void snn_kernel(
    const float* __restrict__ y,
    const float* __restrict__ fc1_b,
    const float* __restrict__ bn1_g, const float* __restrict__ bn1_b,
    const float* __restrict__ bn1_m, const float* __restrict__ bn1_v,
    const float* __restrict__ fc2_w, const float* __restrict__ fc2_b,
    const float* __restrict__ bn2_g, const float* __restrict__ bn2_b,
    const float* __restrict__ bn2_m, const float* __restrict__ bn2_v,
    const float* __restrict__ cls_w, const float* __restrict__ cls_b,
    float* __restrict__ out)
{
    const int lane = threadIdx.x & 63;
    const int wid  = threadIdx.x >> 6;
    const int n0   = blockIdx.x * 64 + wid * 16;
    const int r    = lane & 15;
    const int grp  = lane >> 4;

    short8v Whi[4][2], Wlo[4][2];
#pragma unroll
    for (int T = 0; T < 4; ++T) {
        const int hp = 16 * T + r;
        const float scale = bn2_g[hp] / sqrtf(bn2_v[hp] + EPS);
#pragma unroll
        for (int Hh = 0; Hh < 2; ++Hh) {
            S8U hi, lo;
#pragma unroll
            for (int d = 0; d < 4; ++d) {
                const int kk = 32 * Hh + 8 * grp + 2 * d;
                float w0 = fc2_w[hp * 64 + kk]     * scale;
                float w1 = fc2_w[hp * 64 + kk + 1] * scale;
                unsigned short h0 = bf16rne(w0), h1 = bf16rne(w1);
                unsigned short l0 = bf16rne(w0 - bfbits_to_f(h0));
                unsigned short l1 = bf16rne(w1 - bfbits_to_f(h1));
                hi.u[d] = (unsigned int)h0 | ((unsigned int)h1 << 16);
                lo.u[d] = (unsigned int)l0 | ((unsigned int)l1 << 16);
            }
            Whi[T][Hh] = hi.s;
            Wlo[T][Hh] = lo.s;
        }
    }

    float a1[16];
#pragma unroll
    for (int Hh = 0; Hh < 2; ++Hh)
#pragma unroll
        for (int e = 0; e < 8; ++e) {
            const int hin = 32 * Hh + 8 * grp + e;
            float yv = y[(size_t)(n0 + r) * 64 + hin] + fc1_b[hin];
            float s1v = bn1_g[hin] / sqrtf(bn1_v[hin] + EPS);
            a1[Hh * 8 + e] = (yv - bn1_m[hin]) * s1v + bn1_b[hin];
        }

    float biasD[16];
#pragma unroll
    for (int T = 0; T < 4; ++T)
#pragma unroll
        for (int q = 0; q < 4; ++q) {
            const int hp = 16 * T + 4 * grp + q;
            const float scale = bn2_g[hp] / sqrtf(bn2_v[hp] + EPS);
            biasD[4 * T + q] = (fc2_b[hp] - bn2_m[hp]) * scale + bn2_b[hp];
        }

    float v1[16], v2[16], cnt[16];
#pragma unroll
    for (int i = 0; i < 16; ++i) { v1[i] = 0.f; v2[i] = 0.f; cnt[i] = 0.f; }

#pragma unroll 2
    for (int t = 0; t < 64; ++t) {
        S8U s0, s1f;
#pragma unroll
        for (int Hh = 0; Hh < 2; ++Hh)
#pragma unroll
            for (int d = 0; d < 4; ++d) {
                const int i0 = Hh * 8 + 2 * d;
                float h1a = v1[i0]     + (a1[i0]     - v1[i0])     * 0.5f;
                float h1b = v1[i0 + 1] + (a1[i0 + 1] - v1[i0 + 1]) * 0.5f;
                bool sa = h1a >= 1.f, sb = h1b >= 1.f;
                v1[i0]     = sa ? 0.f : h1a;
                v1[i0 + 1] = sb ? 0.f : h1b;
                unsigned int dw = (sa ? 0x3F80u : 0u) | (sb ? 0x3F800000u : 0u);
                if (Hh == 0) s0.u[d] = dw; else s1f.u[d] = dw;
            }
        const short8v S0 = s0.s, S1 = s1f.s;

        f32x4 acc[4];
#pragma unroll
        for (int T = 0; T < 4; ++T) {
            f32x4 c;
            c[0] = biasD[4 * T + 0]; c[1] = biasD[4 * T + 1];
            c[2] = biasD[4 * T + 2]; c[3] = biasD[4 * T + 3];
            c = __builtin_amdgcn_mfma_f32_16x16x32_bf16(Wlo[T][1], S1, c, 0, 0, 0);
            c = __builtin_amdgcn_mfma_f32_16x16x32_bf16(Wlo[T][0], S0, c, 0, 0, 0);
            c = __builtin_amdgcn_mfma_f32_16x16x32_bf16(Whi[T][1], S1, c, 0, 0, 0);
            c = __builtin_amdgcn_mfma_f32_16x16x32_bf16(Whi[T][0], S0, c, 0, 0, 0);
            acc[T] = c;
        }

#pragma unroll
        for (int T = 0; T < 4; ++T)
#pragma unroll
            for (int q = 0; q < 4; ++q) {
                const int idx = 4 * T + q;
                float z  = acc[T][q];
                float h2 = v2[idx] + (z - v2[idx]) * 0.5f;
                bool s = h2 >= 1.f;
                v2[idx] = s ? 0.f : h2;
                cnt[idx] += s ? 1.f : 0.f;
            }
    }

    float p0 = 0.f, p1 = 0.f, p2 = 0.f, p3 = 0.f;
#pragma unroll
    for (int T = 0; T < 4; ++T)
#pragma unroll
        for (int q = 0; q < 4; ++q) {
            const int hp = 16 * T + 4 * grp + q;
            const float cv = cnt[4 * T + q];
            p0 = fmaf(cv, cls_w[0 * 64 + hp], p0);
            p1 = fmaf(cv, cls_w[1 * 64 + hp], p1);
            p2 = fmaf(cv, cls_w[2 * 64 + hp], p2);
            p3 = fmaf(cv, cls_w[3 * 64 + hp], p3);
        }
    p0 += __shfl_xor(p0, 16); p0 += __shfl_xor(p0, 32);
    p1 += __shfl_xor(p1, 16); p1 += __shfl_xor(p1, 32);
    p2 += __shfl_xor(p2, 16); p2 += __shfl_xor(p2, 32);
    p3 += __shfl_xor(p3, 16); p3 += __shfl_xor(p3, 32);
    if (lane < 16) {
        float4 o;
        o.x = p0 * (1.f / 64.f) + cls_b[0];
        o.y = p1 * (1.f / 64.f) + cls_b[1];
        o.z = p2 * (1.f / 64.f) + cls_b[2];
        o.w = p3 * (1.f / 64.f) + cls_b[3];
        *(float4*)&out[(size_t)(n0 + lane) * 4] = o;
    }
}

extern "C" void kernel_launch(void* const* d_in, const int* in_sizes, int n_in,
                              void* d_out, int out_size, void* d_ws, size_t ws_size,
                              hipStream_t stream) {
    const float* x     = (const float*)d_in[0];
    const float* fc1_w = (const float*)d_in[1];
    const float* fc1_b = (const float*)d_in[2];
    const float* bn1_g = (const float*)d_in[3];
    const float* bn1_b = (const float*)d_in[4];
    const float* bn1_m = (const float*)d_in[5];
    const float* bn1_v = (const float*)d_in[6];
    const float* fc2_w = (const float*)d_in[7];
    const float* fc2_b = (const float*)d_in[8];
    const float* bn2_g = (const float*)d_in[9];
    const float* bn2_b = (const float*)d_in[10];
    const float* bn2_m = (const float*)d_in[11];
    const float* bn2_v = (const float*)d_in[12];
    const float* cls_w = (const float*)d_in[13];
    const float* cls_b = (const float*)d_in[14];

    float*   y  = (float*)d_ws;                            // 4 MB
    ushortt* w3 = (ushortt*)((char*)d_ws + (4 << 20));     // 528 KB

    prep_w3 <<<1056, 256, 0, stream>>>(fc1_w, w3);
    fc1_mfma<<<256,  256, 0, stream>>>(x, w3, y);
    snn_kernel<<<256, 256, 0, stream>>>(y, fc1_b, bn1_g, bn1_b, bn1_m, bn1_v,
                                        fc2_w, fc2_b, bn2_g, bn2_b, bn2_m, bn2_v,
                                        cls_w, cls_b, (float*)d_out);
}

// Round 5
// 78.223 us; speedup vs baseline: 1.3122x; 1.3122x over previous
//
#include <hip/hip_runtime.h>
#include <hip/hip_bf16.h>

#define D_IN 1386
#define EPS 1e-5f
#define CHUNKS 44            // ceil(1386/32)

typedef __attribute__((ext_vector_type(8))) short short8v;
typedef __attribute__((ext_vector_type(4))) float f32x4;
typedef unsigned short ushortt;

__device__ inline unsigned short bf16rne(float f) {
    unsigned int u = __float_as_uint(f);
    u += 0x7FFFu + ((u >> 16) & 1u);
    return (unsigned short)(u >> 16);
}
__device__ inline float bfbits_to_f(unsigned short b) {
    return __uint_as_float(((unsigned int)b) << 16);
}

union S8U { short8v s; unsigned int u[4]; };

// packed pair f32->bf16 (RNE, v_cvt_pk_bf16_f32) + residuals
__device__ inline unsigned int cvt2(float v0, float v1, float& r0, float& r1) {
    union { __hip_bfloat162 b2; unsigned int u; } cv;
    cv.b2 = __float22bfloat162_rn(make_float2(v0, v1));
    r0 = v0 - __uint_as_float((cv.u & 0xFFFFu) << 16);
    r1 = v1 - __uint_as_float(cv.u & 0xFFFF0000u);
    return cv.u;
}
__device__ inline unsigned int cvt2n(float v0, float v1) {
    union { __hip_bfloat162 b2; unsigned int u; } cv;
    cv.b2 = __float22bfloat162_rn(make_float2(v0, v1));
    return cv.u;
}

// ---------------- Kernel 0: precompute triple-split W1 in frag-image order --
// short index: c*6144 + g*512 + l*8 + j -> split_s( w[16T+(l&15)][32c+8*(l>>4)+j] )
// with g = 3*T + s
__global__ __launch_bounds__(256) void prep_w3(const float* __restrict__ w,
                                               ushortt* __restrict__ w3) {
    int idx = blockIdx.x * 256 + threadIdx.x;
    if (idx >= CHUNKS * 6144) return;
    int c   = idx / 6144;
    int rem = idx - c * 6144;
    int g   = rem >> 9;
    int l   = (rem >> 3) & 63;
    int j   = rem & 7;
    int T   = g / 3, s = g - 3 * T;
    int h   = 16 * T + (l & 15);
    int k   = 32 * c + 8 * (l >> 4) + j;
    float v = (k < D_IN) ? w[h * D_IN + k] : 0.f;
    unsigned short hh = bf16rne(v);
    float r1 = v - bfbits_to_f(hh);
    unsigned short mm = bf16rne(r1);
    float r2 = r1 - bfbits_to_f(mm);
    unsigned short ll = bf16rne(r2);
    w3[idx] = (s == 0) ? hh : (s == 1) ? mm : ll;
}

// ---------------- Kernel 1: y = x @ fc1_w.T --------------------------------
// One 1024-thread block per CU: 16 waves = 4 sample-groups (sg) x 4 K-quarters
// (kq, 11 chunks each). wid = 4*kq + sg -> the 4 waves sharing a B-stream
// (same kq) sit on 4 different SIMDs => tight L1 broadcast. Barrier-free main
// loop; single end LDS reduction over kq. 4 waves/SIMD hide load latency.
__device__ inline void loadA(const float* __restrict__ xrow, int c, int g4,
                             float a[8]) {
    if (c < CHUNKS - 1) {
        const float2* p = (const float2*)(xrow + 32 * c);
#pragma unroll
        for (int i = 0; i < 4; ++i) {
            float2 v = p[i];
            a[2 * i] = v.x; a[2 * i + 1] = v.y;
        }
    } else {
#pragma unroll
        for (int j = 0; j < 8; ++j) {
            int kk = 8 * g4 + j;   // + 1376 = global k
            a[j] = (kk < D_IN - 32 * (CHUNKS - 1)) ? xrow[32 * (CHUNKS - 1) + j] : 0.f;
        }
    }
}

__global__ __launch_bounds__(1024, 4) void fc1_mfma(const float* __restrict__ x,
                                                    const ushortt* __restrict__ w3,
                                                    float* __restrict__ y) {
    __shared__ float red[3][4][64][17];   // ~51 KB, used once at the end
    const int t    = threadIdx.x;
    const int lane = t & 63;
    const int wid  = t >> 6;
    const int kq   = wid >> 2;            // K-quarter: chunks [11*kq, 11*kq+11)
    const int sg   = wid & 3;             // sample group of 16
    const int n0   = blockIdx.x * 64 + sg * 16;
    const int r    = lane & 15;
    const int g4   = lane >> 4;
    const float* xrow = x + (size_t)(n0 + r) * D_IN + 8 * g4;
    const int c0 = 11 * kq;

    f32x4 acc[4];
#pragma unroll
    for (int T = 0; T < 4; ++T) acc[T] = (f32x4){0.f, 0.f, 0.f, 0.f};

    float a0[8], a1p[8], a2p[8];
    loadA(xrow, c0, g4, a0);
    loadA(xrow, c0 + 1, g4, a1p);

#pragma unroll
    for (int i = 0; i < 11; ++i) {
        const int c = c0 + i;
        if (i + 2 < 11) loadA(xrow, c + 2, g4, a2p);
        // B fragments: same addresses across the 4 sg-waves of this kq ->
        // L1 broadcast. 12 x 1KB coalesced dwordx4.
        const short8v* bp = (const short8v*)(w3 + (size_t)c * 6144) + lane;
        short8v B0  = bp[0 * 64],  B1  = bp[1 * 64],  B2  = bp[2 * 64];
        short8v B3  = bp[3 * 64],  B4  = bp[4 * 64],  B5  = bp[5 * 64];
        short8v B6  = bp[6 * 64],  B7  = bp[7 * 64],  B8  = bp[8 * 64];
        short8v B9  = bp[9 * 64],  B10 = bp[10 * 64], B11 = bp[11 * 64];
        // triple-split A in-register
        S8U Ah, Am, Al;
#pragma unroll
        for (int d = 0; d < 4; ++d) {
            float m0, m1, l0, l1;
            Ah.u[d] = cvt2(a0[2 * d], a0[2 * d + 1], m0, m1);
            Am.u[d] = cvt2(m0, m1, l0, l1);
            Al.u[d] = cvt2n(l0, l1);
        }
        const short8v XH = Ah.s, XM = Am.s, XL = Al.s;
#pragma unroll
        for (int T = 0; T < 4; ++T) {
            const short8v Bh = (T == 0) ? B0 : (T == 1) ? B3 : (T == 2) ? B6 : B9;
            const short8v Bm = (T == 0) ? B1 : (T == 1) ? B4 : (T == 2) ? B7 : B10;
            const short8v Bl = (T == 0) ? B2 : (T == 1) ? B5 : (T == 2) ? B8 : B11;
            f32x4 cacc = acc[T];
            cacc = __builtin_amdgcn_mfma_f32_16x16x32_bf16(XL, Bh, cacc, 0, 0, 0);
            cacc = __builtin_amdgcn_mfma_f32_16x16x32_bf16(XM, Bm, cacc, 0, 0, 0);
            cacc = __builtin_amdgcn_mfma_f32_16x16x32_bf16(XH, Bl, cacc, 0, 0, 0);
            cacc = __builtin_amdgcn_mfma_f32_16x16x32_bf16(XM, Bh, cacc, 0, 0, 0);
            cacc = __builtin_amdgcn_mfma_f32_16x16x32_bf16(XH, Bm, cacc, 0, 0, 0);
            cacc = __builtin_amdgcn_mfma_f32_16x16x32_bf16(XH, Bh, cacc, 0, 0, 0);
            acc[T] = cacc;
        }
#pragma unroll
        for (int j = 0; j < 8; ++j) { a0[j] = a1p[j]; a1p[j] = a2p[j]; }
    }

    // cross-kq reduction: same-lane registers across the 4 kq waves.
    // stride 17 floats -> bank = 17*idx mod 32 (17 odd) => conflict-free b32.
    if (kq > 0) {
#pragma unroll
        for (int T = 0; T < 4; ++T)
#pragma unroll
            for (int q = 0; q < 4; ++q)
                red[kq - 1][sg][lane][4 * T + q] = acc[T][q];
    }
    __syncthreads();
    if (kq == 0) {
#pragma unroll
        for (int T = 0; T < 4; ++T)
#pragma unroll
            for (int q = 0; q < 4; ++q) {
                float s = acc[T][q]
                        + red[0][sg][lane][4 * T + q]
                        + red[1][sg][lane][4 * T + q]
                        + red[2][sg][lane][4 * T + q];
                y[(size_t)(n0 + 4 * g4 + q) * 64 + 16 * T + r] = s;
            }
    }
}

// ---------------- Kernel 2: 64-step LIF recurrence via MFMA -----------------
// MFMA chain split into hi/lo halves (depth 2 + vector add) to shorten the
// per-step dependent critical path.
__global__ __launch_bounds__(256) void snn_kernel(
    const float* __restrict__ y,
    const float* __restrict__ fc1_b,
    const float* __restrict__ bn1_g, const float* __restrict__ bn1_b,
    const float* __restrict__ bn1_m, const float* __restrict__ bn1_v,
    const float* __restrict__ fc2_w, const float* __restrict__ fc2_b,
    const float* __restrict__ bn2_g, const float* __restrict__ bn2_b,
    const float* __restrict__ bn2_m, const float* __restrict__ bn2_v,
    const float* __restrict__ cls_w, const float* __restrict__ cls_b,
    float* __restrict__ out)
{
    const int lane = threadIdx.x & 63;
    const int wid  = threadIdx.x >> 6;
    const int n0   = blockIdx.x * 64 + wid * 16;
    const int r    = lane & 15;
    const int grp  = lane >> 4;

    short8v Whi[4][2], Wlo[4][2];
#pragma unroll
    for (int T = 0; T < 4; ++T) {
        const int hp = 16 * T + r;
        const float scale = bn2_g[hp] / sqrtf(bn2_v[hp] + EPS);
#pragma unroll
        for (int Hh = 0; Hh < 2; ++Hh) {
            S8U hi, lo;
#pragma unroll
            for (int d = 0; d < 4; ++d) {
                const int kk = 32 * Hh + 8 * grp + 2 * d;
                float w0 = fc2_w[hp * 64 + kk]     * scale;
                float w1 = fc2_w[hp * 64 + kk + 1] * scale;
                unsigned short h0 = bf16rne(w0), h1 = bf16rne(w1);
                unsigned short l0 = bf16rne(w0 - bfbits_to_f(h0));
                unsigned short l1 = bf16rne(w1 - bfbits_to_f(h1));
                hi.u[d] = (unsigned int)h0 | ((unsigned int)h1 << 16);
                lo.u[d] = (unsigned int)l0 | ((unsigned int)l1 << 16);
            }
            Whi[T][Hh] = hi.s;
            Wlo[T][Hh] = lo.s;
        }
    }

    float a1[16];
#pragma unroll
    for (int Hh = 0; Hh < 2; ++Hh)
#pragma unroll
        for (int e = 0; e < 8; ++e) {
            const int hin = 32 * Hh + 8 * grp + e;
            float yv = y[(size_t)(n0 + r) * 64 + hin] + fc1_b[hin];
            float s1v = bn1_g[hin] / sqrtf(bn1_v[hin] + EPS);
            a1[Hh * 8 + e] = (yv - bn1_m[hin]) * s1v + bn1_b[hin];
        }

    float biasD[16];
#pragma unroll
    for (int T = 0; T < 4; ++T)
#pragma unroll
        for (int q = 0; q < 4; ++q) {
            const int hp = 16 * T + 4 * grp + q;
            const float scale = bn2_g[hp] / sqrtf(bn2_v[hp] + EPS);
            biasD[4 * T + q] = (fc2_b[hp] - bn2_m[hp]) * scale + bn2_b[hp];
        }

    float v1[16], v2[16], cnt[16];
#pragma unroll
    for (int i = 0; i < 16; ++i) { v1[i] = 0.f; v2[i] = 0.f; cnt[i] = 0.f; }

#pragma unroll 2
    for (int t = 0; t < 64; ++t) {
        S8U s0, s1f;
#pragma unroll
        for (int Hh = 0; Hh < 2; ++Hh)
#pragma unroll
            for (int d = 0; d < 4; ++d) {
                const int i0 = Hh * 8 + 2 * d;
                float h1a = v1[i0]     + (a1[i0]     - v1[i0])     * 0.5f;
                float h1b = v1[i0 + 1] + (a1[i0 + 1] - v1[i0 + 1]) * 0.5f;
                bool sa = h1a >= 1.f, sb = h1b >= 1.f;
                v1[i0]     = sa ? 0.f : h1a;
                v1[i0 + 1] = sb ? 0.f : h1b;
                unsigned int dw = (sa ? 0x3F80u : 0u) | (sb ? 0x3F800000u : 0u);
                if (Hh == 0) s0.u[d] = dw; else s1f.u[d] = dw;
            }
        const short8v S0 = s0.s, S1 = s1f.s;

        f32x4 acc[4];
#pragma unroll
        for (int T = 0; T < 4; ++T) {
            f32x4 c1;
            c1[0] = biasD[4 * T + 0]; c1[1] = biasD[4 * T + 1];
            c1[2] = biasD[4 * T + 2]; c1[3] = biasD[4 * T + 3];
            f32x4 c2 = (f32x4){0.f, 0.f, 0.f, 0.f};
            c1 = __builtin_amdgcn_mfma_f32_16x16x32_bf16(Whi[T][0], S0, c1, 0, 0, 0);
            c2 = __builtin_amdgcn_mfma_f32_16x16x32_bf16(Wlo[T][0], S0, c2, 0, 0, 0);
            c1 = __builtin_amdgcn_mfma_f32_16x16x32_bf16(Whi[T][1], S1, c1, 0, 0, 0);
            c2 = __builtin_amdgcn_mfma_f32_16x16x32_bf16(Wlo[T][1], S1, c2, 0, 0, 0);
            acc[T] = c1 + c2;
        }

#pragma unroll
        for (int T = 0; T < 4; ++T)
#pragma unroll
            for (int q = 0; q < 4; ++q) {
                const int idx = 4 * T + q;
                float z  = acc[T][q];
                float h2 = v2[idx] + (z - v2[idx]) * 0.5f;
                bool s = h2 >= 1.f;
                v2[idx] = s ? 0.f : h2;
                cnt[idx] += s ? 1.f : 0.f;
            }
    }

    float p0 = 0.f, p1 = 0.f, p2 = 0.f, p3 = 0.f;
#pragma unroll
    for (int T = 0; T < 4; ++T)
#pragma unroll
        for (int q = 0; q < 4; ++q) {
            const int hp = 16 * T + 4 * grp + q;
            const float cv = cnt[4 * T + q];
            p0 = fmaf(cv, cls_w[0 * 64 + hp], p0);
            p1 = fmaf(cv, cls_w[1 * 64 + hp], p1);
            p2 = fmaf(cv, cls_w[2 * 64 + hp], p2);
            p3 = fmaf(cv, cls_w[3 * 64 + hp], p3);
        }
    p0 += __shfl_xor(p0, 16); p0 += __shfl_xor(p0, 32);
    p1 += __shfl_xor(p1, 16); p1 += __shfl_xor(p1, 32);
    p2 += __shfl_xor(p2, 16); p2 += __shfl_xor(p2, 32);
    p3 += __shfl_xor(p3, 16); p3 += __shfl_xor(p3, 32);
    if (lane < 16) {
        float4 o;
        o.x = p0 * (1.f / 64.f) + cls_b[0];
        o.y = p1 * (1.f / 64.f) + cls_b[1];
        o.z = p2 * (1.f / 64.f) + cls_b[2];
        o.w = p3 * (1.f / 64.f) + cls_b[3];
        *(float4*)&out[(size_t)(n0 + lane) * 4] = o;
    }
}

extern "C" void kernel_launch(void* const* d_in, const int* in_sizes, int n_in,
                              void* d_out, int out_size, void* d_ws, size_t ws_size,
                              hipStream_t stream) {
    const float* x     = (const float*)d_in[0];
    const float* fc1_w = (const float*)d_in[1];
    const float* fc1_b = (const float*)d_in[2];
    const float* bn1_g = (const float*)d_in[3];
    const float* bn1_b = (const float*)d_in[4];
    const float* bn1_m = (const float*)d_in[5];
    const float* bn1_v = (const float*)d_in[6];
    const float* fc2_w = (const float*)d_in[7];
    const float* fc2_b = (const float*)d_in[8];
    const float* bn2_g = (const float*)d_in[9];
    const float* bn2_b = (const float*)d_in[10];
    const float* bn2_m = (const float*)d_in[11];
    const float* bn2_v = (const float*)d_in[12];
    const float* cls_w = (const float*)d_in[13];
    const float* cls_b = (const float*)d_in[14];

    float*   y  = (float*)d_ws;                            // 4 MB
    ushortt* w3 = (ushortt*)((char*)d_ws + (4 << 20));     // 528 KB

    prep_w3 <<<1056, 256, 0, stream>>>(fc1_w, w3);
    fc1_mfma<<<256, 1024, 0, stream>>>(x, w3, y);
    snn_kernel<<<256, 256, 0, stream>>>(y, fc1_b, bn1_g, bn1_b, bn1_m, bn1_v,
                                        fc2_w, fc2_b, bn2_g, bn2_b, bn2_m, bn2_v,
                                        cls_w, cls_b, (float*)d_out);
}

// Round 6
// 75.577 us; speedup vs baseline: 1.3581x; 1.0350x over previous
//
#include <hip/hip_runtime.h>
#include <hip/hip_bf16.h>

#define D_IN 1386
#define EPS 1e-5f
#define CHUNKS 44            // ceil(1386/32)

typedef __attribute__((ext_vector_type(8))) short short8v;
typedef __attribute__((ext_vector_type(4))) float f32x4;
typedef unsigned short ushortt;

__device__ inline unsigned short bf16rne(float f) {
    unsigned int u = __float_as_uint(f);
    u += 0x7FFFu + ((u >> 16) & 1u);
    return (unsigned short)(u >> 16);
}
__device__ inline float bfbits_to_f(unsigned short b) {
    return __uint_as_float(((unsigned int)b) << 16);
}

union S8U { short8v s; unsigned int u[4]; };

// packed pair f32->bf16 (RNE, v_cvt_pk_bf16_f32) + residuals
__device__ inline unsigned int cvt2(float v0, float v1, float& r0, float& r1) {
    union { __hip_bfloat162 b2; unsigned int u; } cv;
    cv.b2 = __float22bfloat162_rn(make_float2(v0, v1));
    r0 = v0 - __uint_as_float((cv.u & 0xFFFFu) << 16);
    r1 = v1 - __uint_as_float(cv.u & 0xFFFF0000u);
    return cv.u;
}
__device__ inline unsigned int cvt2n(float v0, float v1) {
    union { __hip_bfloat162 b2; unsigned int u; } cv;
    cv.b2 = __float22bfloat162_rn(make_float2(v0, v1));
    return cv.u;
}

// ---------------- Kernel 0: precompute triple-split W1 in frag-image order --
// short index: c*6144 + g*512 + l*8 + j -> split_s( w[16T+(l&15)][32c+8*(l>>4)+j] )
// with g = 3*T + s
__global__ __launch_bounds__(256) void prep_w3(const float* __restrict__ w,
                                               ushortt* __restrict__ w3) {
    int idx = blockIdx.x * 256 + threadIdx.x;
    if (idx >= CHUNKS * 6144) return;
    int c   = idx / 6144;
    int rem = idx - c * 6144;
    int g   = rem >> 9;
    int l   = (rem >> 3) & 63;
    int j   = rem & 7;
    int T   = g / 3, s = g - 3 * T;
    int h   = 16 * T + (l & 15);
    int k   = 32 * c + 8 * (l >> 4) + j;
    float v = (k < D_IN) ? w[h * D_IN + k] : 0.f;
    unsigned short hh = bf16rne(v);
    float r1 = v - bfbits_to_f(hh);
    unsigned short mm = bf16rne(r1);
    float r2 = r1 - bfbits_to_f(mm);
    unsigned short ll = bf16rne(r2);
    w3[idx] = (s == 0) ? hh : (s == 1) ? mm : ll;
}

// ---------------- Kernel 1: y = x @ fc1_w.T --------------------------------
// Grid 512 x 256thr (2 blocks/CU, 8 waves/CU). Block: 32 samples; wave = one
// K-quarter (kq = wid, 11 chunks) over M=32 (two 16-sample A-sets sharing
// each B-fragment). Chunk loop unrolled x2 with STATIC even/odd register
// sets: a load issued in body i is first used in body i+2 (full-body lead,
// no rotation-forced waits). In-block LDS reduction over kq at the end.
__global__ __launch_bounds__(256, 2) void fc1_mfma(const float* __restrict__ x,
                                                   const ushortt* __restrict__ w3,
                                                   float* __restrict__ y) {
    __shared__ float red[3][64][33];   // 25.3 KB
    const int lane = threadIdx.x & 63;
    const int kq   = threadIdx.x >> 6;   // wave id = K-quarter
    const int n0   = blockIdx.x * 32;
    const int r    = lane & 15;
    const int g4   = lane >> 4;
    const float* xA = x + (size_t)(n0 + r) * D_IN + 8 * g4;
    const float* xB = xA + (size_t)16 * D_IN;
    const int c0   = 11 * kq;

    f32x4 accA[4], accB[4];
#pragma unroll
    for (int T = 0; T < 4; ++T) {
        accA[T] = (f32x4){0.f, 0.f, 0.f, 0.f};
        accB[T] = (f32x4){0.f, 0.f, 0.f, 0.f};
    }

    float aE[16], aO[16];
    short8v BE[12], BO[12];

    auto loadA32 = [&](int c, float (&a)[16]) {
        if (c < CHUNKS - 1) {
            const float2* pA = (const float2*)(xA + 32 * c);
            const float2* pB = (const float2*)(xB + 32 * c);
#pragma unroll
            for (int i = 0; i < 4; ++i) {
                float2 v = pA[i]; a[2 * i] = v.x; a[2 * i + 1] = v.y;
                float2 w = pB[i]; a[8 + 2 * i] = w.x; a[8 + 2 * i + 1] = w.y;
            }
        } else {
#pragma unroll
            for (int j = 0; j < 8; ++j) {
                int kk = 8 * g4 + j;                       // +1376 = global k
                bool ok = kk < (D_IN - 32 * (CHUNKS - 1)); // < 10
                a[j]     = ok ? xA[32 * (CHUNKS - 1) + j] : 0.f;
                a[8 + j] = ok ? xB[32 * (CHUNKS - 1) + j] : 0.f;
            }
        }
    };
    auto loadB12 = [&](int c, short8v (&B)[12]) {
        const short8v* bp = (const short8v*)(w3 + (size_t)c * 6144) + lane;
#pragma unroll
        for (int g = 0; g < 12; ++g) B[g] = bp[g * 64];
    };
    auto body = [&](float (&a)[16], short8v (&B)[12]) {
        S8U Ah0, Am0, Al0, Ah1, Am1, Al1;
#pragma unroll
        for (int d = 0; d < 4; ++d) {
            float m0, m1, l0, l1;
            Ah0.u[d] = cvt2(a[2 * d], a[2 * d + 1], m0, m1);
            Am0.u[d] = cvt2(m0, m1, l0, l1);
            Al0.u[d] = cvt2n(l0, l1);
            Ah1.u[d] = cvt2(a[8 + 2 * d], a[8 + 2 * d + 1], m0, m1);
            Am1.u[d] = cvt2(m0, m1, l0, l1);
            Al1.u[d] = cvt2n(l0, l1);
        }
        const short8v XH0 = Ah0.s, XM0 = Am0.s, XL0 = Al0.s;
        const short8v XH1 = Ah1.s, XM1 = Am1.s, XL1 = Al1.s;
#pragma unroll
        for (int T = 0; T < 4; ++T) {
            const short8v Bh = B[3 * T], Bm = B[3 * T + 1], Bl = B[3 * T + 2];
            f32x4 c1 = accA[T];
            c1 = __builtin_amdgcn_mfma_f32_16x16x32_bf16(XL0, Bh, c1, 0, 0, 0);
            c1 = __builtin_amdgcn_mfma_f32_16x16x32_bf16(XM0, Bm, c1, 0, 0, 0);
            c1 = __builtin_amdgcn_mfma_f32_16x16x32_bf16(XH0, Bl, c1, 0, 0, 0);
            c1 = __builtin_amdgcn_mfma_f32_16x16x32_bf16(XM0, Bh, c1, 0, 0, 0);
            c1 = __builtin_amdgcn_mfma_f32_16x16x32_bf16(XH0, Bm, c1, 0, 0, 0);
            c1 = __builtin_amdgcn_mfma_f32_16x16x32_bf16(XH0, Bh, c1, 0, 0, 0);
            accA[T] = c1;
            f32x4 c2 = accB[T];
            c2 = __builtin_amdgcn_mfma_f32_16x16x32_bf16(XL1, Bh, c2, 0, 0, 0);
            c2 = __builtin_amdgcn_mfma_f32_16x16x32_bf16(XM1, Bm, c2, 0, 0, 0);
            c2 = __builtin_amdgcn_mfma_f32_16x16x32_bf16(XH1, Bl, c2, 0, 0, 0);
            c2 = __builtin_amdgcn_mfma_f32_16x16x32_bf16(XM1, Bh, c2, 0, 0, 0);
            c2 = __builtin_amdgcn_mfma_f32_16x16x32_bf16(XH1, Bm, c2, 0, 0, 0);
            c2 = __builtin_amdgcn_mfma_f32_16x16x32_bf16(XH1, Bh, c2, 0, 0, 0);
            accB[T] = c2;
        }
    };

    // prologue: fill both pipeline stages
    loadA32(c0, aE);     loadB12(c0, BE);
    loadA32(c0 + 1, aO); loadB12(c0 + 1, BO);

#pragma unroll
    for (int j = 0; j < 5; ++j) {
        body(aE, BE);
        if (2 * j + 2 < 11) { loadA32(c0 + 2 * j + 2, aE); loadB12(c0 + 2 * j + 2, BE); }
        body(aO, BO);
        if (2 * j + 3 < 11) { loadA32(c0 + 2 * j + 3, aO); loadB12(c0 + 2 * j + 3, BO); }
    }
    body(aE, BE);   // chunk c0+10

    // in-block reduction over kq (stride-33 pad -> conflict-free b32)
    if (kq > 0) {
#pragma unroll
        for (int T = 0; T < 4; ++T)
#pragma unroll
            for (int q = 0; q < 4; ++q) {
                red[kq - 1][lane][4 * T + q]      = accA[T][q];
                red[kq - 1][lane][16 + 4 * T + q] = accB[T][q];
            }
    }
    __syncthreads();
    if (kq == 0) {
#pragma unroll
        for (int T = 0; T < 4; ++T)
#pragma unroll
            for (int q = 0; q < 4; ++q) {
                float sA = accA[T][q] + red[0][lane][4 * T + q]
                         + red[1][lane][4 * T + q] + red[2][lane][4 * T + q];
                float sB = accB[T][q] + red[0][lane][16 + 4 * T + q]
                         + red[1][lane][16 + 4 * T + q] + red[2][lane][16 + 4 * T + q];
                y[(size_t)(n0 + 4 * g4 + q) * 64 + 16 * T + r] = sA;
                y[(size_t)(n0 + 16 + 4 * g4 + q) * 64 + 16 * T + r] = sB;
            }
    }
}

// ---------------- Kernel 2: 64-step LIF recurrence via MFMA -----------------
__global__ __launch_bounds__(256) void snn_kernel(
    const float* __restrict__ y,
    const float* __restrict__ fc1_b,
    const float* __restrict__ bn1_g, const float* __restrict__ bn1_b,
    const float* __restrict__ bn1_m, const float* __restrict__ bn1_v,
    const float* __restrict__ fc2_w, const float* __restrict__ fc2_b,
    const float* __restrict__ bn2_g, const float* __restrict__ bn2_b,
    const float* __restrict__ bn2_m, const float* __restrict__ bn2_v,
    const float* __restrict__ cls_w, const float* __restrict__ cls_b,
    float* __restrict__ out)
{
    const int lane = threadIdx.x & 63;
    const int wid  = threadIdx.x >> 6;
    const int n0   = blockIdx.x * 64 + wid * 16;
    const int r    = lane & 15;
    const int grp  = lane >> 4;

    short8v Whi[4][2], Wlo[4][2];
#pragma unroll
    for (int T = 0; T < 4; ++T) {
        const int hp = 16 * T + r;
        const float scale = bn2_g[hp] / sqrtf(bn2_v[hp] + EPS);
#pragma unroll
        for (int Hh = 0; Hh < 2; ++Hh) {
            S8U hi, lo;
#pragma unroll
            for (int d = 0; d < 4; ++d) {
                const int kk = 32 * Hh + 8 * grp + 2 * d;
                float w0 = fc2_w[hp * 64 + kk]     * scale;
                float w1 = fc2_w[hp * 64 + kk + 1] * scale;
                unsigned short h0 = bf16rne(w0), h1 = bf16rne(w1);
                unsigned short l0 = bf16rne(w0 - bfbits_to_f(h0));
                unsigned short l1 = bf16rne(w1 - bfbits_to_f(h1));
                hi.u[d] = (unsigned int)h0 | ((unsigned int)h1 << 16);
                lo.u[d] = (unsigned int)l0 | ((unsigned int)l1 << 16);
            }
            Whi[T][Hh] = hi.s;
            Wlo[T][Hh] = lo.s;
        }
    }

    float a1[16];
#pragma unroll
    for (int Hh = 0; Hh < 2; ++Hh)
#pragma unroll
        for (int e = 0; e < 8; ++e) {
            const int hin = 32 * Hh + 8 * grp + e;
            float yv = y[(size_t)(n0 + r) * 64 + hin] + fc1_b[hin];
            float s1v = bn1_g[hin] / sqrtf(bn1_v[hin] + EPS);
            a1[Hh * 8 + e] = (yv - bn1_m[hin]) * s1v + bn1_b[hin];
        }

    float biasD[16];
#pragma unroll
    for (int T = 0; T < 4; ++T)
#pragma unroll
        for (int q = 0; q < 4; ++q) {
            const int hp = 16 * T + 4 * grp + q;
            const float scale = bn2_g[hp] / sqrtf(bn2_v[hp] + EPS);
            biasD[4 * T + q] = (fc2_b[hp] - bn2_m[hp]) * scale + bn2_b[hp];
        }

    float v1[16], v2[16], cnt[16];
#pragma unroll
    for (int i = 0; i < 16; ++i) { v1[i] = 0.f; v2[i] = 0.f; cnt[i] = 0.f; }

#pragma unroll 2
    for (int t = 0; t < 64; ++t) {
        S8U s0, s1f;
#pragma unroll
        for (int Hh = 0; Hh < 2; ++Hh)
#pragma unroll
            for (int d = 0; d < 4; ++d) {
                const int i0 = Hh * 8 + 2 * d;
                float h1a = v1[i0]     + (a1[i0]     - v1[i0])     * 0.5f;
                float h1b = v1[i0 + 1] + (a1[i0 + 1] - v1[i0 + 1]) * 0.5f;
                bool sa = h1a >= 1.f, sb = h1b >= 1.f;
                v1[i0]     = sa ? 0.f : h1a;
                v1[i0 + 1] = sb ? 0.f : h1b;
                unsigned int dw = (sa ? 0x3F80u : 0u) | (sb ? 0x3F800000u : 0u);
                if (Hh == 0) s0.u[d] = dw; else s1f.u[d] = dw;
            }
        const short8v S0 = s0.s, S1 = s1f.s;

        f32x4 acc[4];
#pragma unroll
        for (int T = 0; T < 4; ++T) {
            f32x4 c1;
            c1[0] = biasD[4 * T + 0]; c1[1] = biasD[4 * T + 1];
            c1[2] = biasD[4 * T + 2]; c1[3] = biasD[4 * T + 3];
            f32x4 c2 = (f32x4){0.f, 0.f, 0.f, 0.f};
            c1 = __builtin_amdgcn_mfma_f32_16x16x32_bf16(Whi[T][0], S0, c1, 0, 0, 0);
            c2 = __builtin_amdgcn_mfma_f32_16x16x32_bf16(Wlo[T][0], S0, c2, 0, 0, 0);
            c1 = __builtin_amdgcn_mfma_f32_16x16x32_bf16(Whi[T][1], S1, c1, 0, 0, 0);
            c2 = __builtin_amdgcn_mfma_f32_16x16x32_bf16(Wlo[T][1], S1, c2, 0, 0, 0);
            acc[T] = c1 + c2;
        }

#pragma unroll
        for (int T = 0; T < 4; ++T)
#pragma unroll
            for (int q = 0; q < 4; ++q) {
                const int idx = 4 * T + q;
                float z  = acc[T][q];
                float h2 = v2[idx] + (z - v2[idx]) * 0.5f;
                bool s = h2 >= 1.f;
                v2[idx] = s ? 0.f : h2;
                cnt[idx] += s ? 1.f : 0.f;
            }
    }

    float p0 = 0.f, p1 = 0.f, p2 = 0.f, p3 = 0.f;
#pragma unroll
    for (int T = 0; T < 4; ++T)
#pragma unroll
        for (int q = 0; q < 4; ++q) {
            const int hp = 16 * T + 4 * grp + q;
            const float cv = cnt[4 * T + q];
            p0 = fmaf(cv, cls_w[0 * 64 + hp], p0);
            p1 = fmaf(cv, cls_w[1 * 64 + hp], p1);
            p2 = fmaf(cv, cls_w[2 * 64 + hp], p2);
            p3 = fmaf(cv, cls_w[3 * 64 + hp], p3);
        }
    p0 += __shfl_xor(p0, 16); p0 += __shfl_xor(p0, 32);
    p1 += __shfl_xor(p1, 16); p1 += __shfl_xor(p1, 32);
    p2 += __shfl_xor(p2, 16); p2 += __shfl_xor(p2, 32);
    p3 += __shfl_xor(p3, 16); p3 += __shfl_xor(p3, 32);
    if (lane < 16) {
        float4 o;
        o.x = p0 * (1.f / 64.f) + cls_b[0];
        o.y = p1 * (1.f / 64.f) + cls_b[1];
        o.z = p2 * (1.f / 64.f) + cls_b[2];
        o.w = p3 * (1.f / 64.f) + cls_b[3];
        *(float4*)&out[(size_t)(n0 + lane) * 4] = o;
    }
}

extern "C" void kernel_launch(void* const* d_in, const int* in_sizes, int n_in,
                              void* d_out, int out_size, void* d_ws, size_t ws_size,
                              hipStream_t stream) {
    const float* x     = (const float*)d_in[0];
    const float* fc1_w = (const float*)d_in[1];
    const float* fc1_b = (const float*)d_in[2];
    const float* bn1_g = (const float*)d_in[3];
    const float* bn1_b = (const float*)d_in[4];
    const float* bn1_m = (const float*)d_in[5];
    const float* bn1_v = (const float*)d_in[6];
    const float* fc2_w = (const float*)d_in[7];
    const float* fc2_b = (const float*)d_in[8];
    const float* bn2_g = (const float*)d_in[9];
    const float* bn2_b = (const float*)d_in[10];
    const float* bn2_m = (const float*)d_in[11];
    const float* bn2_v = (const float*)d_in[12];
    const float* cls_w = (const float*)d_in[13];
    const float* cls_b = (const float*)d_in[14];

    float*   y  = (float*)d_ws;                            // 4 MB
    ushortt* w3 = (ushortt*)((char*)d_ws + (4 << 20));     // 528 KB

    prep_w3 <<<1056, 256, 0, stream>>>(fc1_w, w3);
    fc1_mfma<<<512,  256, 0, stream>>>(x, w3, y);
    snn_kernel<<<256, 256, 0, stream>>>(y, fc1_b, bn1_g, bn1_b, bn1_m, bn1_v,
                                        fc2_w, fc2_b, bn2_g, bn2_b, bn2_m, bn2_v,
                                        cls_w, cls_b, (float*)d_out);
}